// Round 1
// baseline (914.566 us; speedup 1.0000x reference)
//
#include <hip/hip_runtime.h>
#include <hip/hip_bf16.h>
#include <stdint.h>

using bf16 = __hip_bfloat16;
typedef __attribute__((ext_vector_type(8))) short bf16x8;
typedef __attribute__((ext_vector_type(4))) float f32x4;
typedef __attribute__((ext_vector_type(8))) unsigned short ushort8;

#define MFMA16(a,b,c) __builtin_amdgcn_mfma_f32_16x16x32_bf16(a,b,c,0,0,0)

static constexpr int Bc = 4, Sc = 2048, HSc = 2048, Hc = 16, KVc = 8, Dc = 128;

__device__ __forceinline__ void gl_lds16(const void* g, void* l) {
  __builtin_amdgcn_global_load_lds((const __attribute__((address_space(1))) uint32_t*)g,
                                   (__attribute__((address_space(3))) uint32_t*)l, 16, 0, 0);
}

__device__ __forceinline__ unsigned short f2bf(float f) {
  bf16 h = __float2bfloat16(f);
  return *reinterpret_cast<unsigned short*>(&h);
}

// ---------------- fp32 -> bf16 convert ----------------
__global__ __launch_bounds__(256) void cvt_f32_bf16(const float* __restrict__ in,
                                                    unsigned short* __restrict__ out, int nvec) {
  int stride = gridDim.x * blockDim.x;
  for (int i = blockIdx.x * blockDim.x + threadIdx.x; i < nvec; i += stride) {
    const float4 a = *(const float4*)(in + (size_t)i * 8);
    const float4 b = *(const float4*)(in + (size_t)i * 8 + 4);
    ushort8 o;
    o[0] = f2bf(a.x); o[1] = f2bf(a.y); o[2] = f2bf(a.z); o[3] = f2bf(a.w);
    o[4] = f2bf(b.x); o[5] = f2bf(b.y); o[6] = f2bf(b.z); o[7] = f2bf(b.w);
    *(ushort8*)(out + (size_t)i * 8) = o;
  }
}

// ---------------- GEMM: C[M][N] = A[M][K] * B[N][K]^T (m97 structure) ----------------
__device__ __forceinline__ void storeC(float* C, size_t i, float v) { C[i] = v; }
__device__ __forceinline__ void storeC(bf16* C, size_t i, float v) { C[i] = __float2bfloat16(v); }

template <typename OUT_T>
__global__ __launch_bounds__(256) void gemm_bt(const bf16* __restrict__ A,
                                               const bf16* __restrict__ B,
                                               OUT_T* __restrict__ C,
                                               int M, int N, int K) {
  const int bm = blockIdx.x;
  const int bn = blockIdx.y;
  __shared__ __align__(16) bf16 sA[128][64];
  __shared__ __align__(16) bf16 sB[128][64];
  const int tid = threadIdx.x;
  const int lane = tid & 63;
  const int wave = tid >> 6;
  const int wr = wave >> 1, wc = wave & 1;
  const int lg = lane >> 4, lr = lane & 15;

  f32x4 acc[4][4];
  #pragma unroll
  for (int m = 0; m < 4; ++m)
    #pragma unroll
    for (int n = 0; n < 4; ++n) acc[m][n] = (f32x4){0.f, 0.f, 0.f, 0.f};

  const int rowA = bm * 128;
  const int rowB = bn * 128;

  for (int k0 = 0; k0 < K; k0 += 64) {
    #pragma unroll
    for (int it = 0; it < 4; ++it) {
      int idx = it * 256 + tid;
      int r = idx >> 3, ch = idx & 7;
      gl_lds16(A + (size_t)(rowA + r) * K + k0 + ch * 8, &sA[r][ch * 8]);
      gl_lds16(B + (size_t)(rowB + r) * K + k0 + ch * 8, &sB[r][ch * 8]);
    }
    __syncthreads();
    #pragma unroll
    for (int kk = 0; kk < 2; ++kk) {
      bf16x8 af[4], bfr[4];
      #pragma unroll
      for (int m = 0; m < 4; ++m)
        af[m] = *(const bf16x8*)&sA[wr * 64 + m * 16 + lr][kk * 32 + lg * 8];
      #pragma unroll
      for (int n = 0; n < 4; ++n)
        bfr[n] = *(const bf16x8*)&sB[wc * 64 + n * 16 + lr][kk * 32 + lg * 8];
      #pragma unroll
      for (int m = 0; m < 4; ++m)
        #pragma unroll
        for (int n = 0; n < 4; ++n)
          acc[m][n] = MFMA16(af[m], bfr[n], acc[m][n]);
    }
    __syncthreads();
  }
  #pragma unroll
  for (int m = 0; m < 4; ++m)
    #pragma unroll
    for (int n = 0; n < 4; ++n)
      #pragma unroll
      for (int r = 0; r < 4; ++r) {
        size_t row = rowA + wr * 64 + m * 16 + lg * 4 + r;
        size_t col = rowB + wc * 64 + n * 16 + lr;
        storeC(C, row * (size_t)N + col, acc[m][n][r]);
      }
}

// ---------------- RMSNorm + RoPE on Q and K ----------------
// qkv: [B*S][4096] bf16 (Q: cols 0..2047, K: 2048..3071, V: 3072..4095)
// Qn: [B][H][S][D] bf16 ; Kn: [B][KV][S][D] bf16
__global__ __launch_bounds__(256) void norm_rope(const bf16* __restrict__ qkv,
                                                 const float* __restrict__ cosT,
                                                 const float* __restrict__ sinT,
                                                 const float* __restrict__ qw,
                                                 const float* __restrict__ kw,
                                                 bf16* __restrict__ Qn, bf16* __restrict__ Kn) {
  const int bs = blockIdx.x;
  const int s = bs & (Sc - 1);
  const int b = bs >> 11;
  const int wave = threadIdx.x >> 6, lane = threadIdx.x & 63;
  const float c0 = cosT[(size_t)s * Dc + lane];
  const float c1 = cosT[(size_t)s * Dc + 64 + lane];
  const float s0 = sinT[(size_t)s * Dc + lane];
  const float s1 = sinT[(size_t)s * Dc + 64 + lane];
  const bf16* row = qkv + (size_t)bs * 4096;
  #pragma unroll
  for (int i = 0; i < 6; ++i) {
    int head = wave * 6 + i;  // 0..15 = Q heads, 16..23 = K heads
    bool isQ = head < 16;
    int col = head * Dc;
    float x0 = __bfloat162float(row[col + lane]);
    float x1 = __bfloat162float(row[col + 64 + lane]);
    float ss = x0 * x0 + x1 * x1;
    #pragma unroll
    for (int off = 32; off; off >>= 1) ss += __shfl_xor(ss, off);
    float inv = rsqrtf(ss * (1.0f / 128.0f) + 1e-6f);
    const float* w = isQ ? qw : kw;
    float n0 = x0 * inv * w[lane];
    float n1 = x1 * inv * w[lane + 64];
    float o0 = n0 * c0 - n1 * s0;
    float o1 = n1 * c1 + n0 * s1;
    size_t base;
    bf16* dst;
    if (isQ) { base = ((size_t)(b * Hc + head) * Sc + s) * Dc; dst = Qn; }
    else     { base = ((size_t)(b * KVc + (head - 16)) * Sc + s) * Dc; dst = Kn; }
    dst[base + lane] = __float2bfloat16(o0);
    dst[base + 64 + lane] = __float2bfloat16(o1);
  }
}

// ---------------- V transpose: qkv V slice -> Vt [B][KV][D][S] ----------------
__global__ __launch_bounds__(256) void v_transpose(const bf16* __restrict__ qkv,
                                                   bf16* __restrict__ Vt) {
  const int s0 = blockIdx.x * 64;
  const int bk = blockIdx.y;  // b*8+kv
  __shared__ __align__(16) bf16 tile[64][136];
  const int tid = threadIdx.x;
  const size_t srcbase = ((size_t)(bk >> 3) * Sc + s0) * 4096 + 3072 + (size_t)(bk & 7) * Dc;
  #pragma unroll
  for (int it = 0; it < 4; ++it) {
    int idx = it * 256 + tid;
    int r = idx >> 4, ch = idx & 15;
    *(bf16x8*)&tile[r][ch * 8] = *(const bf16x8*)(qkv + srcbase + (size_t)r * 4096 + ch * 8);
  }
  __syncthreads();
  const size_t dstbase = (size_t)bk * Dc * Sc + s0;
  #pragma unroll
  for (int it = 0; it < 4; ++it) {
    int idx = it * 256 + tid;
    int d = idx >> 3, scc = idx & 7;
    bf16x8 o;
    #pragma unroll
    for (int j = 0; j < 8; ++j) o[j] = *(const short*)&tile[scc * 8 + j][d];
    *(bf16x8*)(Vt + dstbase + (size_t)d * Sc + scc * 8) = o;
  }
}

// ---------------- causal GQA flash attention ----------------
// Qn [B][H][S][D], Kn [B][KV][S][D], Vt [B][KV][D][S] -> Out [B][S][H*D] bf16
__global__ __launch_bounds__(256) void flash_kernel(const bf16* __restrict__ Qn,
                                                    const bf16* __restrict__ Kn,
                                                    const bf16* __restrict__ Vt,
                                                    bf16* __restrict__ Out) {
  const int q0 = blockIdx.x * 64;
  const int bh = blockIdx.y;
  const int b = bh >> 4, h = bh & 15;
  const int kv = h >> 1;
  const int tid = threadIdx.x;
  const int wave = tid >> 6, lane = tid & 63;
  const int lg = lane >> 4, lr = lane & 15;

  __shared__ __align__(16) bf16 sK[64][128];
  __shared__ __align__(16) bf16 sV[128][64];      // [d][s_local]
  __shared__ __align__(16) bf16 sP[4][16][72];    // per-wave P, padded to keep 16B align

  const bf16* qbase = Qn + ((size_t)(b * Hc + h) * Sc + q0 + wave * 16 + lr) * Dc;
  bf16x8 qf[4];
  #pragma unroll
  for (int kk = 0; kk < 4; ++kk) qf[kk] = *(const bf16x8*)(qbase + kk * 32 + lg * 8);

  f32x4 oacc[8];
  #pragma unroll
  for (int i = 0; i < 8; ++i) oacc[i] = (f32x4){0.f, 0.f, 0.f, 0.f};
  float m_run[4], l_run[4];
  #pragma unroll
  for (int r = 0; r < 4; ++r) { m_run[r] = -3.0e38f; l_run[r] = 0.f; }

  const bf16* kb = Kn + ((size_t)(b * KVc + kv) * Sc) * Dc;
  const bf16* vb = Vt + ((size_t)(b * KVc + kv) * Dc) * Sc;
  const float scl = 0.08838834764831845f * 1.4426950408889634f;  // 1/sqrt(D) * log2(e)

  for (int k0 = 0; k0 <= q0; k0 += 64) {
    #pragma unroll
    for (int it = 0; it < 4; ++it) {
      int idx = it * 256 + tid;
      gl_lds16(kb + (size_t)(k0 + (idx >> 4)) * Dc + (idx & 15) * 8, &sK[idx >> 4][(idx & 15) * 8]);
    }
    #pragma unroll
    for (int it = 0; it < 4; ++it) {
      int idx = it * 256 + tid;
      gl_lds16(vb + (size_t)(idx >> 3) * Sc + k0 + (idx & 7) * 8, &sV[idx >> 3][(idx & 7) * 8]);
    }
    __syncthreads();

    float t[4][4];
    #pragma unroll
    for (int c = 0; c < 4; ++c) {
      f32x4 sacc = (f32x4){0.f, 0.f, 0.f, 0.f};
      #pragma unroll
      for (int kk = 0; kk < 4; ++kk) {
        bf16x8 kf = *(const bf16x8*)&sK[c * 16 + lr][kk * 32 + lg * 8];
        sacc = MFMA16(qf[kk], kf, sacc);
      }
      int kg = k0 + c * 16 + lr;
      #pragma unroll
      for (int r = 0; r < 4; ++r) {
        int qg = q0 + wave * 16 + lg * 4 + r;
        t[c][r] = (kg <= qg) ? sacc[r] * scl : -3.0e38f;
      }
    }

    float alpha[4];
    #pragma unroll
    for (int r = 0; r < 4; ++r) {
      float mx = fmaxf(fmaxf(t[0][r], t[1][r]), fmaxf(t[2][r], t[3][r]));
      mx = fmaxf(mx, __shfl_xor(mx, 1));
      mx = fmaxf(mx, __shfl_xor(mx, 2));
      mx = fmaxf(mx, __shfl_xor(mx, 4));
      mx = fmaxf(mx, __shfl_xor(mx, 8));
      float mnew = fmaxf(m_run[r], mx);
      alpha[r] = exp2f(m_run[r] - mnew);
      m_run[r] = mnew;
      float sum = 0.f;
      #pragma unroll
      for (int c = 0; c < 4; ++c) { t[c][r] = exp2f(t[c][r] - mnew); sum += t[c][r]; }
      sum += __shfl_xor(sum, 1);
      sum += __shfl_xor(sum, 2);
      sum += __shfl_xor(sum, 4);
      sum += __shfl_xor(sum, 8);
      l_run[r] = l_run[r] * alpha[r] + sum;
    }
    #pragma unroll
    for (int dc = 0; dc < 8; ++dc)
      #pragma unroll
      for (int r = 0; r < 4; ++r) oacc[dc][r] *= alpha[r];
    #pragma unroll
    for (int c = 0; c < 4; ++c)
      #pragma unroll
      for (int r = 0; r < 4; ++r)
        sP[wave][lg * 4 + r][c * 16 + lr] = __float2bfloat16(t[c][r]);
    __syncthreads();
    #pragma unroll
    for (int kk2 = 0; kk2 < 2; ++kk2) {
      bf16x8 pf = *(const bf16x8*)&sP[wave][lr][kk2 * 32 + lg * 8];
      #pragma unroll
      for (int dc = 0; dc < 8; ++dc) {
        bf16x8 vf = *(const bf16x8*)&sV[dc * 16 + lr][kk2 * 32 + lg * 8];
        oacc[dc] = MFMA16(pf, vf, oacc[dc]);
      }
    }
    __syncthreads();
  }

  #pragma unroll
  for (int r = 0; r < 4; ++r) l_run[r] = 1.f / l_run[r];
  #pragma unroll
  for (int dc = 0; dc < 8; ++dc)
    #pragma unroll
    for (int r = 0; r < 4; ++r) {
      size_t row = (size_t)b * Sc + q0 + wave * 16 + lg * 4 + r;
      Out[row * (size_t)(Hc * Dc) + h * Dc + dc * 16 + lr] =
          __float2bfloat16(oacc[dc][r] * l_run[r]);
    }
}

// ---------------- launch ----------------
extern "C" void kernel_launch(void* const* d_in, const int* in_sizes, int n_in,
                              void* d_out, int out_size, void* d_ws, size_t ws_size,
                              hipStream_t stream) {
  const float* x    = (const float*)d_in[0];
  const float* cosT = (const float*)d_in[1];
  const float* sinT = (const float*)d_in[2];
  const float* wq   = (const float*)d_in[3];
  const float* wk   = (const float*)d_in[4];
  const float* wv   = (const float*)d_in[5];
  const float* wo   = (const float*)d_in[6];
  const float* qnw  = (const float*)d_in[7];
  const float* knw  = (const float*)d_in[8];
  float* out = (float*)d_out;

  const size_t MB = 1ull << 20;
  char* ws = (char*)d_ws;
  bf16* xb   = (bf16*)(ws + 0);        // 32MB  [8192][2048]
  bf16* wqkv = (bf16*)(ws + 32 * MB);  // 16MB  [4096][2048]
  bf16* wob  = (bf16*)(ws + 48 * MB);  // 8MB   [2048][2048]
  bf16* qkv  = (bf16*)(ws + 56 * MB);  // 64MB  [8192][4096]
  bf16* Qn   = (bf16*)(ws + 120 * MB); // 32MB  [B][H][S][D]
  bf16* Kn   = (bf16*)(ws + 152 * MB); // 16MB  [B][KV][S][D]
  bf16* Vt   = (bf16*)(ws + 168 * MB); // 16MB  [B][KV][D][S]
  bf16* attn = (bf16*)(ws + 184 * MB); // 32MB  [8192][2048]

  auto cvt = [&](const float* src, bf16* dst, int n) {
    int nvec = n >> 3;
    int blocks = (nvec + 255) / 256;
    if (blocks > 8192) blocks = 8192;
    cvt_f32_bf16<<<blocks, 256, 0, stream>>>(src, (unsigned short*)dst, nvec);
  };
  cvt(x, xb, 4 * 2048 * 2048);
  cvt(wq, wqkv, 2048 * 2048);
  cvt(wk, wqkv + 2048 * 2048, 1024 * 2048);
  cvt(wv, wqkv + 3072 * 2048, 1024 * 2048);
  cvt(wo, wob, 2048 * 2048);

  gemm_bt<bf16><<<dim3(64, 32), 256, 0, stream>>>(xb, wqkv, qkv, 8192, 4096, 2048);
  norm_rope<<<8192, 256, 0, stream>>>(qkv, cosT, sinT, qnw, knw, Qn, Kn);
  v_transpose<<<dim3(32, 32), 256, 0, stream>>>(qkv, Vt);
  flash_kernel<<<dim3(32, 64), 256, 0, stream>>>(Qn, Kn, Vt, attn);
  gemm_bt<float><<<dim3(64, 16), 256, 0, stream>>>(attn, wob, out, 8192, 2048, 2048);
}

// Round 2
// 540.481 us; speedup vs baseline: 1.6921x; 1.6921x over previous
//
#include <hip/hip_runtime.h>
#include <hip/hip_bf16.h>
#include <stdint.h>

using bf16 = __hip_bfloat16;
typedef __attribute__((ext_vector_type(8))) short bf16x8;
typedef __attribute__((ext_vector_type(4))) float f32x4;
typedef __attribute__((ext_vector_type(8))) unsigned short ushort8;

#define MFMA16(a,b,c) __builtin_amdgcn_mfma_f32_16x16x32_bf16(a,b,c,0,0,0)

static constexpr int Bc = 4, Sc = 2048, HSc = 2048, Hc = 16, KVc = 8, Dc = 128;

__device__ __forceinline__ void gl_lds16(const void* g, void* l) {
  __builtin_amdgcn_global_load_lds((const __attribute__((address_space(1))) uint32_t*)g,
                                   (__attribute__((address_space(3))) uint32_t*)l, 16, 0, 0);
}

__device__ __forceinline__ unsigned short f2bf(float f) {
  bf16 h = __float2bfloat16(f);
  return *reinterpret_cast<unsigned short*>(&h);
}

// ---------------- fp32 -> bf16 convert ----------------
__global__ __launch_bounds__(256) void cvt_f32_bf16(const float* __restrict__ in,
                                                    unsigned short* __restrict__ out, int nvec) {
  int stride = gridDim.x * blockDim.x;
  for (int i = blockIdx.x * blockDim.x + threadIdx.x; i < nvec; i += stride) {
    const float4 a = *(const float4*)(in + (size_t)i * 8);
    const float4 b = *(const float4*)(in + (size_t)i * 8 + 4);
    ushort8 o;
    o[0] = f2bf(a.x); o[1] = f2bf(a.y); o[2] = f2bf(a.z); o[3] = f2bf(a.w);
    o[4] = f2bf(b.x); o[5] = f2bf(b.y); o[6] = f2bf(b.z); o[7] = f2bf(b.w);
    *(ushort8*)(out + (size_t)i * 8) = o;
  }
}

// ---------------- GEMM: C[M][N] = A[M][K] * B[N][K]^T (m97 structure + T1 XCD swizzle) ----------------
__device__ __forceinline__ void storeC(float* C, size_t i, float v) { C[i] = v; }
__device__ __forceinline__ void storeC(bf16* C, size_t i, float v) { C[i] = __float2bfloat16(v); }

template <typename OUT_T>
__global__ __launch_bounds__(256) void gemm_bt(const bf16* __restrict__ A,
                                               const bf16* __restrict__ B,
                                               OUT_T* __restrict__ C,
                                               int M, int N, int K) {
  // XCD-aware bijective swizzle (nwg % 8 == 0 for all our shapes)
  const int nwg = gridDim.x * gridDim.y;
  const int wgid = blockIdx.y * gridDim.x + blockIdx.x;
  const int cpx = nwg >> 3;
  const int swz = (wgid & 7) * cpx + (wgid >> 3);
  const int bm = swz % gridDim.x;
  const int bn = swz / gridDim.x;

  __shared__ __align__(16) bf16 sA[128][64];
  __shared__ __align__(16) bf16 sB[128][64];
  const int tid = threadIdx.x;
  const int lane = tid & 63;
  const int wave = tid >> 6;
  const int wr = wave >> 1, wc = wave & 1;
  const int lg = lane >> 4, lr = lane & 15;

  f32x4 acc[4][4];
  #pragma unroll
  for (int m = 0; m < 4; ++m)
    #pragma unroll
    for (int n = 0; n < 4; ++n) acc[m][n] = (f32x4){0.f, 0.f, 0.f, 0.f};

  const int rowA = bm * 128;
  const int rowB = bn * 128;

  for (int k0 = 0; k0 < K; k0 += 64) {
    #pragma unroll
    for (int it = 0; it < 4; ++it) {
      int idx = it * 256 + tid;
      int r = idx >> 3, ch = idx & 7;
      gl_lds16(A + (size_t)(rowA + r) * K + k0 + ch * 8, &sA[r][ch * 8]);
      gl_lds16(B + (size_t)(rowB + r) * K + k0 + ch * 8, &sB[r][ch * 8]);
    }
    __syncthreads();
    #pragma unroll
    for (int kk = 0; kk < 2; ++kk) {
      bf16x8 af[4], bfr[4];
      #pragma unroll
      for (int m = 0; m < 4; ++m)
        af[m] = *(const bf16x8*)&sA[wr * 64 + m * 16 + lr][kk * 32 + lg * 8];
      #pragma unroll
      for (int n = 0; n < 4; ++n)
        bfr[n] = *(const bf16x8*)&sB[wc * 64 + n * 16 + lr][kk * 32 + lg * 8];
      #pragma unroll
      for (int m = 0; m < 4; ++m)
        #pragma unroll
        for (int n = 0; n < 4; ++n)
          acc[m][n] = MFMA16(af[m], bfr[n], acc[m][n]);
    }
    __syncthreads();
  }
  #pragma unroll
  for (int m = 0; m < 4; ++m)
    #pragma unroll
    for (int n = 0; n < 4; ++n)
      #pragma unroll
      for (int r = 0; r < 4; ++r) {
        size_t row = rowA + wr * 64 + m * 16 + lg * 4 + r;
        size_t col = rowB + wc * 64 + n * 16 + lr;
        storeC(C, row * (size_t)N + col, acc[m][n][r]);
      }
}

// ---------------- RMSNorm + RoPE on Q and K ----------------
__global__ __launch_bounds__(256) void norm_rope(const bf16* __restrict__ qkv,
                                                 const float* __restrict__ cosT,
                                                 const float* __restrict__ sinT,
                                                 const float* __restrict__ qw,
                                                 const float* __restrict__ kw,
                                                 bf16* __restrict__ Qn, bf16* __restrict__ Kn) {
  const int bs = blockIdx.x;
  const int s = bs & (Sc - 1);
  const int b = bs >> 11;
  const int wave = threadIdx.x >> 6, lane = threadIdx.x & 63;
  const float c0 = cosT[(size_t)s * Dc + lane];
  const float c1 = cosT[(size_t)s * Dc + 64 + lane];
  const float s0 = sinT[(size_t)s * Dc + lane];
  const float s1 = sinT[(size_t)s * Dc + 64 + lane];
  const bf16* row = qkv + (size_t)bs * 4096;
  #pragma unroll
  for (int i = 0; i < 6; ++i) {
    int head = wave * 6 + i;  // 0..15 = Q heads, 16..23 = K heads
    bool isQ = head < 16;
    int col = head * Dc;
    float x0 = __bfloat162float(row[col + lane]);
    float x1 = __bfloat162float(row[col + 64 + lane]);
    float ss = x0 * x0 + x1 * x1;
    #pragma unroll
    for (int off = 32; off; off >>= 1) ss += __shfl_xor(ss, off);
    float inv = rsqrtf(ss * (1.0f / 128.0f) + 1e-6f);
    const float* w = isQ ? qw : kw;
    float n0 = x0 * inv * w[lane];
    float n1 = x1 * inv * w[lane + 64];
    float o0 = n0 * c0 - n1 * s0;
    float o1 = n1 * c1 + n0 * s1;
    size_t base;
    bf16* dst;
    if (isQ) { base = ((size_t)(b * Hc + head) * Sc + s) * Dc; dst = Qn; }
    else     { base = ((size_t)(b * KVc + (head - 16)) * Sc + s) * Dc; dst = Kn; }
    dst[base + lane] = __float2bfloat16(o0);
    dst[base + 64 + lane] = __float2bfloat16(o1);
  }
}

// ---------------- V transpose: qkv V slice -> Vt [B][KV][D][S] ----------------
__global__ __launch_bounds__(256) void v_transpose(const bf16* __restrict__ qkv,
                                                   bf16* __restrict__ Vt) {
  const int s0 = blockIdx.x * 64;
  const int bk = blockIdx.y;  // b*8+kv
  __shared__ __align__(16) bf16 tile[64][136];
  const int tid = threadIdx.x;
  const size_t srcbase = ((size_t)(bk >> 3) * Sc + s0) * 4096 + 3072 + (size_t)(bk & 7) * Dc;
  #pragma unroll
  for (int it = 0; it < 4; ++it) {
    int idx = it * 256 + tid;
    int r = idx >> 4, ch = idx & 15;
    *(bf16x8*)&tile[r][ch * 8] = *(const bf16x8*)(qkv + srcbase + (size_t)r * 4096 + ch * 8);
  }
  __syncthreads();
  const size_t dstbase = (size_t)bk * Dc * Sc + s0;
  #pragma unroll
  for (int it = 0; it < 4; ++it) {
    int idx = it * 256 + tid;
    int d = idx >> 3, scc = idx & 7;
    bf16x8 o;
    #pragma unroll
    for (int j = 0; j < 8; ++j) o[j] = *(const short*)&tile[scc * 8 + j][d];
    *(bf16x8*)(Vt + dstbase + (size_t)d * Sc + scc * 8) = o;
  }
}

// ---------------- causal GQA flash attention (T2-swizzled K/V LDS) ----------------
// Qn [B][H][S][D], Kn [B][KV][S][D], Vt [B][KV][D][S] -> Out [B][S][H*D] bf16
__global__ __launch_bounds__(256) void flash_kernel(const bf16* __restrict__ Qn,
                                                    const bf16* __restrict__ Kn,
                                                    const bf16* __restrict__ Vt,
                                                    bf16* __restrict__ Out) {
  // heavy-first causal schedule: qi descending so long blocks launch first
  const int qi = 31 - (blockIdx.x >> 6);
  const int bh = blockIdx.x & 63;
  const int q0 = qi * 64;
  const int b = bh >> 4, h = bh & 15;
  const int kv = h >> 1;
  const int tid = threadIdx.x;
  const int wave = tid >> 6, lane = tid & 63;
  const int lg = lane >> 4, lr = lane & 15;
  const int rm = lr & 7;  // read-side XOR mask (row & 7)

  __shared__ __align__(16) bf16 sK[64][128];   // XOR-swizzled: slot ^= row&7
  __shared__ __align__(16) bf16 sV[128][64];   // [d][s_local], XOR-swizzled
  __shared__ __align__(16) bf16 sP[4][16][72]; // per-wave P, padded (stride 144B: conflict-free)

  const bf16* qbase = Qn + ((size_t)(b * Hc + h) * Sc + q0 + wave * 16 + lr) * Dc;
  bf16x8 qf[4];
  #pragma unroll
  for (int kk = 0; kk < 4; ++kk) qf[kk] = *(const bf16x8*)(qbase + kk * 32 + lg * 8);

  f32x4 oacc[8];
  #pragma unroll
  for (int i = 0; i < 8; ++i) oacc[i] = (f32x4){0.f, 0.f, 0.f, 0.f};
  float m_run[4], l_run[4];
  #pragma unroll
  for (int r = 0; r < 4; ++r) { m_run[r] = -3.0e38f; l_run[r] = 0.f; }

  const bf16* kb = Kn + ((size_t)(b * KVc + kv) * Sc) * Dc;
  const bf16* vb = Vt + ((size_t)(b * KVc + kv) * Dc) * Sc;
  const float scl = 0.08838834764831845f * 1.4426950408889634f;  // 1/sqrt(D) * log2(e)

  for (int k0 = 0; k0 <= q0; k0 += 64) {
    // stage K: linear LDS dest, inverse-swizzled global source (rule 21)
    #pragma unroll
    for (int it = 0; it < 4; ++it) {
      int idx = it * 256 + tid;
      int r = idx >> 4, ps = idx & 15;
      int ls = ps ^ (r & 7);
      gl_lds16(kb + (size_t)(k0 + r) * Dc + ls * 8, &sK[r][ps * 8]);
    }
    // stage V (transposed layout [d][s]), same swizzle on 16B slots
    #pragma unroll
    for (int it = 0; it < 4; ++it) {
      int idx = it * 256 + tid;
      int r = idx >> 3, ps = idx & 7;
      int ls = ps ^ (r & 7);
      gl_lds16(vb + (size_t)r * Sc + k0 + ls * 8, &sV[r][ps * 8]);
    }
    __syncthreads();

    float t[4][4];
    #pragma unroll
    for (int c = 0; c < 4; ++c) {
      f32x4 sacc = (f32x4){0.f, 0.f, 0.f, 0.f};
      #pragma unroll
      for (int kk = 0; kk < 4; ++kk) {
        bf16x8 kf = *(const bf16x8*)&sK[c * 16 + lr][((kk * 4 + lg) ^ rm) * 8];
        sacc = MFMA16(qf[kk], kf, sacc);
      }
      int kg = k0 + c * 16 + lr;
      #pragma unroll
      for (int r = 0; r < 4; ++r) {
        int qg = q0 + wave * 16 + lg * 4 + r;
        t[c][r] = (kg <= qg) ? sacc[r] * scl : -3.0e38f;
      }
    }

    float alpha[4];
    #pragma unroll
    for (int r = 0; r < 4; ++r) {
      float mx = fmaxf(fmaxf(t[0][r], t[1][r]), fmaxf(t[2][r], t[3][r]));
      mx = fmaxf(mx, __shfl_xor(mx, 1));
      mx = fmaxf(mx, __shfl_xor(mx, 2));
      mx = fmaxf(mx, __shfl_xor(mx, 4));
      mx = fmaxf(mx, __shfl_xor(mx, 8));
      float mnew = fmaxf(m_run[r], mx);
      alpha[r] = exp2f(m_run[r] - mnew);
      m_run[r] = mnew;
      float sum = 0.f;
      #pragma unroll
      for (int c = 0; c < 4; ++c) { t[c][r] = exp2f(t[c][r] - mnew); sum += t[c][r]; }
      sum += __shfl_xor(sum, 1);
      sum += __shfl_xor(sum, 2);
      sum += __shfl_xor(sum, 4);
      sum += __shfl_xor(sum, 8);
      l_run[r] = l_run[r] * alpha[r] + sum;
    }
    #pragma unroll
    for (int dc = 0; dc < 8; ++dc)
      #pragma unroll
      for (int r = 0; r < 4; ++r) oacc[dc][r] *= alpha[r];
    #pragma unroll
    for (int c = 0; c < 4; ++c)
      #pragma unroll
      for (int r = 0; r < 4; ++r)
        sP[wave][lg * 4 + r][c * 16 + lr] = __float2bfloat16(t[c][r]);
    __syncthreads();
    #pragma unroll
    for (int kk2 = 0; kk2 < 2; ++kk2) {
      bf16x8 pf = *(const bf16x8*)&sP[wave][lr][kk2 * 32 + lg * 8];
      #pragma unroll
      for (int dc = 0; dc < 8; ++dc) {
        bf16x8 vf = *(const bf16x8*)&sV[dc * 16 + lr][((kk2 * 4 + lg) ^ rm) * 8];
        oacc[dc] = MFMA16(pf, vf, oacc[dc]);
      }
    }
    __syncthreads();
  }

  #pragma unroll
  for (int r = 0; r < 4; ++r) l_run[r] = 1.f / l_run[r];
  #pragma unroll
  for (int dc = 0; dc < 8; ++dc)
    #pragma unroll
    for (int r = 0; r < 4; ++r) {
      size_t row = (size_t)b * Sc + q0 + wave * 16 + lg * 4 + r;
      Out[row * (size_t)(Hc * Dc) + h * Dc + dc * 16 + lr] =
          __float2bfloat16(oacc[dc][r] * l_run[r]);
    }
}

// ---------------- launch ----------------
extern "C" void kernel_launch(void* const* d_in, const int* in_sizes, int n_in,
                              void* d_out, int out_size, void* d_ws, size_t ws_size,
                              hipStream_t stream) {
  const float* x    = (const float*)d_in[0];
  const float* cosT = (const float*)d_in[1];
  const float* sinT = (const float*)d_in[2];
  const float* wq   = (const float*)d_in[3];
  const float* wk   = (const float*)d_in[4];
  const float* wv   = (const float*)d_in[5];
  const float* wo   = (const float*)d_in[6];
  const float* qnw  = (const float*)d_in[7];
  const float* knw  = (const float*)d_in[8];
  float* out = (float*)d_out;

  const size_t MB = 1ull << 20;
  char* ws = (char*)d_ws;
  bf16* xb   = (bf16*)(ws + 0);        // 32MB  [8192][2048]
  bf16* wqkv = (bf16*)(ws + 32 * MB);  // 16MB  [4096][2048]
  bf16* wob  = (bf16*)(ws + 48 * MB);  // 8MB   [2048][2048]
  bf16* qkv  = (bf16*)(ws + 56 * MB);  // 64MB  [8192][4096]
  bf16* Qn   = (bf16*)(ws + 120 * MB); // 32MB  [B][H][S][D]
  bf16* Kn   = (bf16*)(ws + 152 * MB); // 16MB  [B][KV][S][D]
  bf16* Vt   = (bf16*)(ws + 168 * MB); // 16MB  [B][KV][D][S]
  bf16* attn = (bf16*)(ws + 184 * MB); // 32MB  [8192][2048]

  auto cvt = [&](const float* src, bf16* dst, int n) {
    int nvec = n >> 3;
    int blocks = (nvec + 255) / 256;
    if (blocks > 8192) blocks = 8192;
    cvt_f32_bf16<<<blocks, 256, 0, stream>>>(src, (unsigned short*)dst, nvec);
  };
  cvt(x, xb, 4 * 2048 * 2048);
  cvt(wq, wqkv, 2048 * 2048);
  cvt(wk, wqkv + 2048 * 2048, 1024 * 2048);
  cvt(wv, wqkv + 3072 * 2048, 1024 * 2048);
  cvt(wo, wob, 2048 * 2048);

  gemm_bt<bf16><<<dim3(64, 32), 256, 0, stream>>>(xb, wqkv, qkv, 8192, 4096, 2048);
  norm_rope<<<8192, 256, 0, stream>>>(qkv, cosT, sinT, qnw, knw, Qn, Kn);
  v_transpose<<<dim3(32, 32), 256, 0, stream>>>(qkv, Vt);
  flash_kernel<<<2048, 256, 0, stream>>>(Qn, Kn, Vt, attn);
  gemm_bt<float><<<dim3(64, 16), 256, 0, stream>>>(attn, wob, out, 8192, 2048, 2048);
}